// Round 1
// 575.697 us; speedup vs baseline: 1.0010x; 1.0010x over previous
//
#include <hip/hip_runtime.h>

#define NB 256
#define NN 64
#define NT 4096

// K1: variance per (b,i) row over 4096 elements, ddof=1.
// One wave per row, 4 rows per block: 16 float4 loads/lane (256 B/lane),
// pure shuffle reduction -> no LDS, no __syncthreads.
__global__ __launch_bounds__(256) void var_kernel(const float* __restrict__ x,
                                                  float* __restrict__ e) {
    int row  = blockIdx.x * 4 + (threadIdx.x >> 6);
    int lane = threadIdx.x & 63;
    const float4* xr = (const float4*)(x + (size_t)row * NT);
    float s = 0.f, ss = 0.f;
#pragma unroll
    for (int k = 0; k < 16; ++k) {
        float4 v = xr[lane + k * 64];
        s  += (v.x + v.y) + (v.z + v.w);
        ss += (v.x * v.x + v.y * v.y) + (v.z * v.z + v.w * v.w);
    }
#pragma unroll
    for (int off = 32; off > 0; off >>= 1) {
        s  += __shfl_down(s, off);
        ss += __shfl_down(ss, off);
    }
    if (lane == 0) {
        float mean = s * (1.0f / NT);
        e[row] = (ss - (float)NT * mean * mean) * (1.0f / (NT - 1));
    }
}

// K2: softmax attention weights per batch. Logits factor as
// SCALE*(A*e_i*e_j + Bq*e_i + Bk*e_j + C). One thread per row i.
// Writes attn to d_out AND W'^T (transposed, residual identity folded:
// diagonal softmax weight is exactly 0 since exp(-1e9 - m) underflows,
// so W'[i][i] = 1 exactly) to workspace. The TRANSPOSED layout makes
// each j-slice W'T[j][0..63] contiguous -> out_kernel fetches it with
// scalar s_load_dwordx16, and the store here is lane-coalesced.
__global__ __launch_bounds__(64) void attn_kernel(const float* __restrict__ e,
                                                  const float* __restrict__ wq,
                                                  const float* __restrict__ bq,
                                                  const float* __restrict__ wk,
                                                  const float* __restrict__ bk,
                                                  float* __restrict__ attn_out,
                                                  float* __restrict__ wpT) {
    int b = blockIdx.x;
    int i = threadIdx.x;
    float A = 0.f, Bq = 0.f, Bk = 0.f, C = 0.f;
#pragma unroll
    for (int h = 0; h < 16; ++h) {
        A  += wq[h] * wk[h];
        Bq += wq[h] * bk[h];
        Bk += bq[h] * wk[h];
        C  += bq[h] * bk[h];
    }
    __shared__ float es[NN];
    es[i] = e[b * NN + i];
    __syncthreads();
    float ei = es[i];
    float l[NN];
    float m = -3.0e38f;
#pragma unroll
    for (int j = 0; j < NN; ++j) {
        float v = 0.25f * (A * ei * es[j] + Bq * ei + Bk * es[j] + C);
        if (j == i) v = -1.0e9f;   // diagonal mask
        l[j] = v;
        m = fmaxf(m, v);
    }
    float sum = 0.f;
#pragma unroll
    for (int j = 0; j < NN; ++j) {
        float ev = expf(l[j] - m);  // diagonal underflows to exactly 0
        l[j] = ev;
        sum += ev;
    }
    float inv = 1.0f / sum;
    float* dst = attn_out + (size_t)b * (NN * NN) + i * NN;
    float* wt  = wpT      + (size_t)b * (NN * NN);
#pragma unroll
    for (int j = 0; j < NN; ++j) {
        float w = l[j] * inv;
        dst[j] = w;                              // attn row (thread-local)
        wt[j * NN + i] = (j == i) ? 1.0f : w;    // W'^T, coalesced over lanes
    }
}

// K3: out[b,i,t] = sum_j W'[i][j] * x[b,j,t]  with W' = attn + I.
// Accumulator-resident structure: thread owns ONE column t and all 64
// output rows as acc[64] (accumulators canNOT be rematerialized, unlike
// the previous version's xv[] cache that regalloc demoted to re-loads —
// VGPR_Count was 36). Per j: one x load (read exactly once per thread)
// + 64 FMAs against wave-uniform W'T[j][i] (contiguous -> s_load_dwordx16,
// scalar pipe, zero VALU cost). ~75 VGPRs -> ~6 waves/SIMD.
__global__ __launch_bounds__(256) void out_kernel(const float* __restrict__ x,
                                                  const float* __restrict__ WpT,
                                                  float* __restrict__ out) {
    int blk = blockIdx.x;
    int b = blk >> 4;                 // 16 chunks of 256 columns per batch
    int t = (blk & 15) * 256 + threadIdx.x;
    const float* xb = x + (size_t)b * (NN * NT) + t;
    const float* Wb = WpT + (size_t)b * (NN * NN);

    float acc[NN];
#pragma unroll
    for (int i = 0; i < NN; ++i) acc[i] = 0.f;

#pragma unroll 2
    for (int j = 0; j < NN; ++j) {
        float xv = xb[(size_t)j * NT];
        const float* Wr = Wb + j * NN;     // block-uniform -> s_loads
#pragma unroll
        for (int i = 0; i < NN; ++i) acc[i] = fmaf(Wr[i], xv, acc[i]);
    }

    float* ob = out + (size_t)b * (NN * NT) + t;
#pragma unroll
    for (int i = 0; i < NN; ++i) ob[(size_t)i * NT] = acc[i];
}

extern "C" void kernel_launch(void* const* d_in, const int* in_sizes, int n_in,
                              void* d_out, int out_size, void* d_ws, size_t ws_size,
                              hipStream_t stream) {
    const float* x  = (const float*)d_in[0];
    const float* wq = (const float*)d_in[1];
    const float* bq = (const float*)d_in[2];
    const float* wk = (const float*)d_in[3];
    const float* bk = (const float*)d_in[4];
    float* out  = (float*)d_out;
    float* attn = out + (size_t)NB * NN * NT;     // second output region
    float* e    = (float*)d_ws;                   // 16384 floats
    float* wpT  = (float*)d_ws + NB * NN;         // W'^T = (attn + I)^T, 4 MB

    var_kernel<<<NB * NN / 4, 256, 0, stream>>>(x, e);
    attn_kernel<<<NB, 64, 0, stream>>>(e, wq, bq, wk, bk, attn, wpT);
    out_kernel<<<NB * 16, 256, 0, stream>>>(x, wpT, out);
}